// Round 8
// baseline (97.059 us; speedup 1.0000x reference)
//
#include <hip/hip_runtime.h>
#include <hip/hip_bf16.h>

// out[n,h] = x[n,h] * weight[h] + bias[h]
// N=16384, H=4096, fp32 in/out. Pure streaming.
// R7 structure (hoisted w/b, normal loads, sc0 sc1 nt store-bypass) with
// unroll x4: 4 independent loads in flight before any store, testing whether
// 85us is issue-limited or bus-limited. FETCH pinned at 131MB (L3 replacement
// floor for x == L3 capacity); WRITE 262MB.

typedef float v4f __attribute__((ext_vector_type(4)));

__device__ __forceinline__ void store_bypass(v4f val, v4f* addr) {
    asm volatile("global_store_dwordx4 %0, %1, off sc0 sc1 nt"
                 :: "v"(addr), "v"(val)
                 : "memory");
}

__global__ __launch_bounds__(256) void scale_shift_f32_ntbyp4(
    const v4f* __restrict__ x,
    const v4f* __restrict__ w,
    const v4f* __restrict__ b,
    v4f* __restrict__ out,
    int total4, int h4mask) {
    const int tid = blockIdx.x * blockDim.x + threadIdx.x;
    const int stride = gridDim.x * blockDim.x;   // host guarantees: multiple of (h4mask+1)

    const int h4 = tid & h4mask;                 // loop-invariant by construction
    const v4f wv = w[h4];
    const v4f bv = b[h4];

    int i = tid;
    for (; i + 3 * stride < total4; i += 4 * stride) {
        v4f x0 = x[i];
        v4f x1 = x[i + stride];
        v4f x2 = x[i + 2 * stride];
        v4f x3 = x[i + 3 * stride];
        v4f o0 = x0 * wv + bv;
        v4f o1 = x1 * wv + bv;
        v4f o2 = x2 * wv + bv;
        v4f o3 = x3 * wv + bv;
        store_bypass(o0, &out[i]);
        store_bypass(o1, &out[i + stride]);
        store_bypass(o2, &out[i + 2 * stride]);
        store_bypass(o3, &out[i + 3 * stride]);
    }
    for (; i < total4; i += stride) {
        v4f o = x[i] * wv + bv;
        store_bypass(o, &out[i]);
    }
}

extern "C" void kernel_launch(void* const* d_in, const int* in_sizes, int n_in,
                              void* d_out, int out_size, void* d_ws, size_t ws_size,
                              hipStream_t stream) {
    const float* x = (const float*)d_in[0];
    const float* w = (const float*)d_in[1];
    const float* b = (const float*)d_in[2];
    float* out = (float*)d_out;

    const int H = in_sizes[1];           // 4096
    const int total = out_size;          // N*H = 67,108,864
    const int total4 = total / 4;
    const int h4 = H / 4;                // 1024, power of two
    const int h4mask = h4 - 1;

    const int block = 256;
    int grid = 2048;                     // 2048*256 = 524288, multiple of 1024
    while ((long long)grid * block % h4 != 0 && grid > 1) grid--;

    scale_shift_f32_ntbyp4<<<grid, block, 0, stream>>>(
        (const v4f*)x, (const v4f*)w, (const v4f*)b,
        (v4f*)out, total4, h4mask);
}

// Round 9
// 89.994 us; speedup vs baseline: 1.0785x; 1.0785x over previous
//
#include <hip/hip_runtime.h>
#include <hip/hip_bf16.h>

// out[n,h] = x[n,h] * weight[h] + bias[h]
// N=16384, H=4096, fp32 in/out. Pure streaming. BEST KNOWN: 85.08 us (R7).
//
// Final form + why each choice matters (A/B evidence):
// - hoisted w/b: (grid*block) % (H/4) == 0 -> h4 thread-invariant (R4: neutral
//   vs per-iter loads, but free).
// - x2 unroll ONLY: x4 regressed 85->97 us (R8: VGPR 12->20, occ 70->61%,
//   wider address spread).
// - normal loads: nt loads bypass L3 and regressed (R3); x is exactly
//   L3-sized and sits ~50% resident (FETCH 131MB vs 262MB full-stream).
// - stores via inline-asm global_store_dwordx4 sc0 sc1 nt: full cache bypass
//   for the write-once stream; stops out from thrashing L2/L3 against x
//   (R6 nt-builtin: 94.7us; sc0sc1nt: 85.1us).
// Effective BW 6.16 TB/s ~= 98% of the 6.29 TB/s measured copy ceiling.

typedef float v4f __attribute__((ext_vector_type(4)));

__device__ __forceinline__ void store_bypass(v4f val, v4f* addr) {
    asm volatile("global_store_dwordx4 %0, %1, off sc0 sc1 nt"
                 :: "v"(addr), "v"(val)
                 : "memory");
}

__global__ __launch_bounds__(256) void scale_shift_f32_ntbyp(
    const v4f* __restrict__ x,
    const v4f* __restrict__ w,
    const v4f* __restrict__ b,
    v4f* __restrict__ out,
    int total4, int h4mask) {
    const int tid = blockIdx.x * blockDim.x + threadIdx.x;
    const int stride = gridDim.x * blockDim.x;   // host guarantees: multiple of (h4mask+1)

    const int h4 = tid & h4mask;                 // loop-invariant by construction
    const v4f wv = w[h4];
    const v4f bv = b[h4];

    int i = tid;
    for (; i + stride < total4; i += 2 * stride) {
        v4f x0 = x[i];                           // normal load: ~50% L3 hits
        v4f x1 = x[i + stride];
        v4f o0 = x0 * wv + bv;
        v4f o1 = x1 * wv + bv;
        store_bypass(o0, &out[i]);
        store_bypass(o1, &out[i + stride]);
    }
    for (; i < total4; i += stride) {
        v4f o = x[i] * wv + bv;
        store_bypass(o, &out[i]);
    }
}

extern "C" void kernel_launch(void* const* d_in, const int* in_sizes, int n_in,
                              void* d_out, int out_size, void* d_ws, size_t ws_size,
                              hipStream_t stream) {
    const float* x = (const float*)d_in[0];
    const float* w = (const float*)d_in[1];
    const float* b = (const float*)d_in[2];
    float* out = (float*)d_out;

    const int H = in_sizes[1];           // 4096
    const int total = out_size;          // N*H = 67,108,864
    const int total4 = total / 4;
    const int h4 = H / 4;                // 1024, power of two
    const int h4mask = h4 - 1;

    const int block = 256;
    int grid = 2048;                     // 2048*256 = 524288, multiple of 1024
    while ((long long)grid * block % h4 != 0 && grid > 1) grid--;

    scale_shift_f32_ntbyp<<<grid, block, 0, stream>>>(
        (const v4f*)x, (const v4f*)w, (const v4f*)b,
        (v4f*)out, total4, h4mask);
}